// Round 2
// baseline (161.714 us; speedup 1.0000x reference)
//
#include <hip/hip_runtime.h>
#include <math.h>

#define NN_ 256      // nodes per graph
#define BB_ 64       // batch
#define FF_ 5        // features
#define NE_ 65536    // NN_*NN_

// workspace layout in floats (~3.4 MB used, L2/L3-resident)
// Operators stored DE-NORMALIZED and transposed: Op[k*256+j] = pure weight
//   SLA = w, SL1 = z0*w, SL3 = z1*w, SL5 = z2*w   (no dis, no 0.45, no diag)
// Chain applies  y_j = 0.1*x_j + 0.45*dis_j * sum_k Op[k,j]*(dis_k*x_k).
#define OFF_SLA 0        // pure w
#define OFF_SL1 65536    // z0*w
#define OFF_SL3 131072   // z1*w
#define OFF_SL5 196608   // z2*w
#define OFF_DIS 262144   // 256 floats
#define OFF_CNT 262400   // 512 ints: per-graph sync counters cnt[g*8+l]
#define OFF_POOL 263168  // 64*4*128 floats: per-(g,q) pooled partials
#define OFF_S0  327680   // 64*2048 floats: S exchange buffer (even stages)
#define OFF_S1  458752   // 64*2048 floats: S exchange buffer (odd stages)

// ---------------------------------------------------------------------------
// K1: block i = operator row i. One p-row gather serves BOTH the deg
// reduction (dis_i) and the four operator writes. Block 0 also zeroes the
// inter-block sync counters used by K2 (kernel boundary = visibility fence).
// ---------------------------------------------------------------------------
__global__ __launch_bounds__(256) void build_all(
    const float* __restrict__ p, const float* __restrict__ u_rb,
    const float* __restrict__ a_uc, const float* __restrict__ b_uc,
    const float* __restrict__ u_pi, float* __restrict__ ws,
    float* __restrict__ out) {
  const int i = blockIdx.x, j = threadIdx.x;

  if (i == 0) {  // zero K2's sync counters (poisoned ws each iteration)
    int* cnt = (int*)(ws + OFF_CNT);
    cnt[j] = 0;
    cnt[256 + j] = 0;
  }

  const int t = (i >= j) ? (i * (i + 1) / 2 + j) : (j * (j + 1) / 2 + i);
  const float w = p[t];

  __shared__ float sh[NN_];
  __shared__ float slg[3];
  __shared__ float skld[3];
  sh[j] = fabsf(w);

  if (j < 3) {
    const int l = j;
    const float au = fmaxf(a_uc[l], -10.0f);
    const float bu = fminf(fmaxf(b_uc[l], -10.0f), 50.0f);
    const float a = log1pf(expf(au));
    const float b = log1pf(expf(bu));
    const float up = fminf(fmaxf(u_pi[l], 1e-6f), 1.0f - 1e-6f);
    const float pi = powf(1.0f - powf(up, 1.0f / b), 1.0f / a);
    slg[l] = logf(pi) - log1pf(-pi);
    if (i == 0) {
      out[193 + l] = pi;  // drop_rates
      float x = b, dg = 0.0f;
      while (x < 6.0f) { dg -= 1.0f / x; x += 1.0f; }
      const float inv = 1.0f / x, inv2 = inv * inv;
      dg += logf(x) - 0.5f * inv
            - inv2 * (1.0f / 12.0f - inv2 * (1.0f / 120.0f - inv2 * (1.0f / 252.0f)));
      const float euler = 0.577215664901532f;
      skld[l] = (1.0f - 0.8f / a) * (-euler - dg - 1.0f / b)
                + logf(a * b + 1e-10f) - logf(0.8f) - (b - 1.0f) / b;
    }
  }
  __syncthreads();

  // deg_i = sum_j |W[i,j]| via LDS tree reduction over the row we just loaded
  for (int s = NN_ / 2; s > 0; s >>= 1) {
    if (j < s) sh[j] += sh[j + s];
    __syncthreads();
  }
  if (j == 0) {
    const float deg = sh[0];
    ws[OFF_DIS + i] = (deg > 0.0f) ? (1.0f / sqrtf(deg)) : 0.0f;
    if (i == 0) out[192] = skld[0] + skld[1] + skld[2];  // kld_loss
  }

  // pure (un-normalized) operators; coalesced u_rb reads and ws writes
  const float lg0 = slg[0];
  const float lg1 = slg[1];
  const float lg2 = slg[2];
  const int idx = i * NN_ + j;
  const float inv_temp = 1.0f / 0.6f;

  ws[OFF_SLA + idx] = w;

  float u, v;
  u = fminf(fmaxf(u_rb[0 * NE_ + idx], 1e-6f), 1.0f - 1e-6f);
  v = (lg0 + logf(u) - log1pf(-u)) * inv_temp;
  ws[OFF_SL1 + idx] = w / (1.0f + expf(-v));

  u = fminf(fmaxf(u_rb[1 * NE_ + idx], 1e-6f), 1.0f - 1e-6f);
  v = (lg1 + logf(u) - log1pf(-u)) * inv_temp;
  ws[OFF_SL3 + idx] = w / (1.0f + expf(-v));

  u = fminf(fmaxf(u_rb[2 * NE_ + idx], 1e-6f), 1.0f - 1e-6f);
  v = (lg2 + logf(u) - log1pf(-u)) * inv_temp;
  ws[OFF_SL5 + idx] = w / (1.0f + expf(-v));
}

// ---------------------------------------------------------------------------
// K2: chain over 256 blocks x 256 threads — block (g,q) owns j-quarter q of
// graph g. Full S = dis*X lives in LDS (8 KB); per stage the 4 sibling
// blocks exchange their 2 KB dis*Y quarters through a double-buffered global
// area and sync via per-(g,stage) agent-scope counters (all blocks
// co-resident: 4 waves / ~19 KB LDS each). Head: per-quarter pooled
// partials -> q==0 block combines and applies fc.
// ---------------------------------------------------------------------------
__global__ __launch_bounds__(256) void chain_mb(
    const float* __restrict__ x0g, float* __restrict__ ws,
    const float* __restrict__ lin_w, const float* __restrict__ lin_b,
    const float* __restrict__ fc_w, const float* __restrict__ fc_b,
    float* __restrict__ out) {
  const int g = blockIdx.x >> 2;   // graph
  const int q = blockIdx.x & 3;    // output j-quarter
  const int tid = threadIdx.x;
  const int j0 = tid & 63;         // j within quarter (lane)
  const int kq = tid >> 6;         // wave = k-quarter
  const int j = q * 64 + j0;       // absolute output node

  __shared__ float S[NN_ * 8];       // 8 KB: dis-scaled current X (full)
  __shared__ float Xo[64 * 8];       // 2 KB: own-quarter unscaled X
  __shared__ float part[4 * 64 * 8]; // 8 KB: partials [kq][j0][f] (+x temp)
  __shared__ float sdis[NN_];

  int* const cnt = (int*)(ws + OFF_CNT) + g * 8;
  float* const Sg0 = ws + OFF_S0 + g * 2048;
  float* const Sg1 = ws + OFF_S1 + g * 2048;

  for (int ii = tid; ii < NN_; ii += 256) sdis[ii] = ws[OFF_DIS + ii];
  // stage x[g] ([256][5] row-major) into part as padded [256][8], pads = 0
  for (int idx = tid; idx < 2048; idx += 256) {
    const int i = idx >> 3, f = idx & 7;
    part[idx] = (f < 5) ? x0g[g * (NN_ * FF_) + i * 5 + f] : 0.0f;
  }
  __syncthreads();
  for (int idx = tid; idx < 2048; idx += 256)
    S[idx] = sdis[idx >> 3] * part[idx];
  for (int idx = tid; idx < 512; idx += 256)
    Xo[idx] = part[q * 512 + idx];          // own quarter, pads 0
  __syncthreads();

#pragma unroll
  for (int l = 0; l < 5; ++l) {
    const float* __restrict__ Op =
        ws + (l == 0 ? OFF_SL1 : l == 2 ? OFF_SL3 : l == 4 ? OFF_SL5 : OFF_SLA)
        + j;
    float* const Sn = (l & 1) ? Sg1 : Sg0;  // exchange buffer this stage
    float a0 = 0.f, a1 = 0.f, a2 = 0.f, a3 = 0.f, a4 = 0.f;
    const int kb = kq * 64;
#pragma unroll 8
    for (int k = kb; k < kb + 64; ++k) {
      const float wv = Op[k * NN_];                 // coalesced global (L2)
      const float4 xv = *(const float4*)(S + k * 8);  // LDS broadcast
      const float x4 = S[k * 8 + 4];
      a0 += wv * xv.x; a1 += wv * xv.y;
      a2 += wv * xv.z; a3 += wv * xv.w;
      a4 += wv * x4;
    }
    float4 t03 = {a0, a1, a2, a3};
    *(float4*)(part + tid * 8) = t03;   // part[kq][j0][0..3]
    part[tid * 8 + 4] = a4;             // pads 5..7 stay 0 from staging
    __syncthreads();
    // combine 4 k-quarters for own 64 j's (512 padded entries)
    for (int idx = tid; idx < 512; idx += 256) {
      const float sum = part[idx] + part[512 + idx] + part[1024 + idx] +
                        part[1536 + idx];
      const float djj = sdis[q * 64 + (idx >> 3)];
      float y = 0.1f * Xo[idx] + 0.45f * djj * sum;
      if (l == 2) y = fmaxf(y, 0.f);
      Xo[idx] = y;
      if (l < 4) Sn[q * 512 + idx] = djj * y;   // publish own quarter
    }
    __syncthreads();  // Xo/LDS done; all global stores drained (vmcnt(0))
    if (l < 4) {
      if (tid == 0) {
        __hip_atomic_fetch_add(&cnt[l], 1, __ATOMIC_ACQ_REL,
                               __HIP_MEMORY_SCOPE_AGENT);
        while (__hip_atomic_load(&cnt[l], __ATOMIC_ACQUIRE,
                                 __HIP_MEMORY_SCOPE_AGENT) < 4)
          __builtin_amdgcn_s_sleep(2);
      }
      __syncthreads();
      // reload full S for next stage
      for (int idx = tid; idx < 2048; idx += 256) S[idx] = Sn[idx];
      __syncthreads();
    }
  }

  // head: Xo holds O own-quarter (64 x 5, padded 8).
  // relu(O@lin_w+lin_b) partial-pooled over own 64 rows.
  const int k = tid & 127, seg = tid >> 7;  // 2 segs x 32 rows
  const float lw0 = lin_w[0 * 128 + k];
  const float lw1 = lin_w[1 * 128 + k];
  const float lw2 = lin_w[2 * 128 + k];
  const float lw3 = lin_w[3 * 128 + k];
  const float lw4 = lin_w[4 * 128 + k];
  const float lb = lin_b[k];
  float acc = 0.f;
  const int r0 = seg * 32;
#pragma unroll 4
  for (int r = r0; r < r0 + 32; ++r) {
    const float4 ov = *(const float4*)(Xo + r * 8);  // LDS broadcast
    const float o4 = Xo[r * 8 + 4];
    const float vv = lb + lw0 * ov.x + lw1 * ov.y + lw2 * ov.z +
                     lw3 * ov.w + lw4 * o4;
    acc += fmaxf(vv, 0.f);
  }
  part[seg * 128 + k] = acc;
  __syncthreads();
  if (tid < 128)
    ws[OFF_POOL + (g * 4 + q) * 128 + tid] = part[tid] + part[128 + tid];
  __syncthreads();  // drain pooled-slot stores before release
  if (tid == 0)
    __hip_atomic_fetch_add(&cnt[4], 1, __ATOMIC_ACQ_REL,
                           __HIP_MEMORY_SCOPE_AGENT);

  if (q == 0) {  // finisher block: combine 4 pooled slots, apply fc
    if (tid == 0) {
      while (__hip_atomic_load(&cnt[4], __ATOMIC_ACQUIRE,
                               __HIP_MEMORY_SCOPE_AGENT) < 4)
        __builtin_amdgcn_s_sleep(2);
    }
    __syncthreads();
    if (tid < 128) {
      const float* pp = ws + OFF_POOL + g * 512;
      part[tid] = (pp[tid] + pp[128 + tid]) + pp[256 + tid] + pp[384 + tid];
    }
    __syncthreads();
    if (tid < 3) {
      float s = fc_b[tid];
      for (int kk = 0; kk < 128; ++kk) s += part[kk] * fc_w[kk * 3 + tid];
      out[g * 3 + tid] = s;
    }
  }
}

// ---------------------------------------------------------------------------
extern "C" void kernel_launch(void* const* d_in, const int* in_sizes, int n_in,
                              void* d_out, int out_size, void* d_ws,
                              size_t ws_size, hipStream_t stream) {
  const float* x      = (const float*)d_in[0];
  const float* p      = (const float*)d_in[1];
  const float* a_uc   = (const float*)d_in[2];
  const float* b_uc   = (const float*)d_in[3];
  const float* u_pi   = (const float*)d_in[4];
  const float* u_rb   = (const float*)d_in[5];
  const float* lin_w  = (const float*)d_in[6];
  const float* lin_b  = (const float*)d_in[7];
  const float* fc_w   = (const float*)d_in[8];
  const float* fc_b   = (const float*)d_in[9];
  // d_in[10] edge_index, d_in[11] batch: fully deterministic, never read.
  float* out = (float*)d_out;
  float* ws  = (float*)d_ws;

  build_all<<<256, 256, 0, stream>>>(p, u_rb, a_uc, b_uc, u_pi, ws, out);
  chain_mb<<<256, 256, 0, stream>>>(x, ws, lin_w, lin_b, fc_w, fc_b, out);
}

// Round 3
// 131.208 us; speedup vs baseline: 1.2325x; 1.2325x over previous
//
#include <hip/hip_runtime.h>
#include <math.h>

#define NN_ 256      // nodes per graph
#define BB_ 64       // batch
#define FF_ 5        // features
#define NE_ 65536    // NN_*NN_

// workspace layout in floats (~1 MB, L2/L3-resident)
// Operators stored DE-NORMALIZED and transposed: Op[k*256+j] = pure weight
//   SLA = w, SL1 = z0*w, SL3 = z1*w, SL5 = z2*w   (no dis, no 0.45, no diag)
// Chain applies  y_j = 0.1*x_j + 0.45*dis_j * sum_k Op[k,j]*(dis_k*x_k).
#define OFF_SLA 0        // pure w
#define OFF_SL1 65536    // z0*w
#define OFF_SL3 131072   // z1*w
#define OFF_SL5 196608   // z2*w
#define OFF_DIS 262144   // 256 floats

// ---------------------------------------------------------------------------
// K1: layer-split build. blockIdx = l*256 + i  (l = 0..3, i = operator row).
//   l in {0,1,2}: build the z_l-scaled operator row i (ONE transcendental
//                 chain per thread instead of three -> 3x shorter serial
//                 latency; 1024 blocks -> 4 blocks/CU -> 4 waves/SIMD).
//   l == 3:       write plain-w row + deg/dis reduction (shfl, 1 barrier);
//                 block (i=0,l=3) lane 0 emits kld_loss + drop_rates.
// Arithmetic identical to the round-1 version (absmax 0.0).
// ---------------------------------------------------------------------------
__global__ __launch_bounds__(256) void build_all(
    const float* __restrict__ p, const float* __restrict__ u_rb,
    const float* __restrict__ a_uc, const float* __restrict__ b_uc,
    const float* __restrict__ u_pi, float* __restrict__ ws,
    float* __restrict__ out) {
  const int blk = blockIdx.x;
  const int l = blk >> 8;      // 0..3
  const int i = blk & 255;     // operator row
  const int j = threadIdx.x;
  const int t = (i >= j) ? (i * (i + 1) / 2 + j) : (j * (j + 1) / 2 + i);
  const float w = p[t];
  const int idx = i * NN_ + j;

  if (l == 3) {
    ws[OFF_SLA + idx] = w;
    // deg_i = sum_j |W[i,j]|: shfl wave-reduce + tiny LDS combine
    float v = fabsf(w);
#pragma unroll
    for (int off = 32; off > 0; off >>= 1) v += __shfl_down(v, off, 64);
    __shared__ float red[4];
    if ((j & 63) == 0) red[j >> 6] = v;
    __syncthreads();
    if (j == 0) {
      const float deg = red[0] + red[1] + red[2] + red[3];
      ws[OFF_DIS + i] = (deg > 0.0f) ? (1.0f / sqrtf(deg)) : 0.0f;
      if (i == 0) {
        // scalar tail: kld_loss + drop_rates for the 3 layers
        float kld_sum = 0.0f;
        const float euler = 0.577215664901532f;
        for (int ll = 0; ll < 3; ++ll) {
          const float au = fmaxf(a_uc[ll], -10.0f);
          const float bu = fminf(fmaxf(b_uc[ll], -10.0f), 50.0f);
          const float a = log1pf(expf(au));
          const float b = log1pf(expf(bu));
          const float up = fminf(fmaxf(u_pi[ll], 1e-6f), 1.0f - 1e-6f);
          const float pi = powf(1.0f - powf(up, 1.0f / b), 1.0f / a);
          out[193 + ll] = pi;  // drop_rates
          float x = b, dg = 0.0f;
          while (x < 6.0f) { dg -= 1.0f / x; x += 1.0f; }
          const float inv = 1.0f / x, inv2 = inv * inv;
          dg += logf(x) - 0.5f * inv
                - inv2 * (1.0f / 12.0f - inv2 * (1.0f / 120.0f - inv2 * (1.0f / 252.0f)));
          kld_sum += (1.0f - 0.8f / a) * (-euler - dg - 1.0f / b)
                     + logf(a * b + 1e-10f) - logf(0.8f) - (b - 1.0f) / b;
        }
        out[192] = kld_sum;  // kld_loss
      }
    }
    return;
  }

  // l in 0..2: logits computed once per block (lane 0), LDS broadcast
  __shared__ float slg;
  if (j == 0) {
    const float au = fmaxf(a_uc[l], -10.0f);
    const float bu = fminf(fmaxf(b_uc[l], -10.0f), 50.0f);
    const float a = log1pf(expf(au));
    const float b = log1pf(expf(bu));
    const float up = fminf(fmaxf(u_pi[l], 1e-6f), 1.0f - 1e-6f);
    const float pi = powf(1.0f - powf(up, 1.0f / b), 1.0f / a);
    slg = logf(pi) - log1pf(-pi);
  }
  const float u = fminf(fmaxf(u_rb[l * NE_ + idx], 1e-6f), 1.0f - 1e-6f);
  __syncthreads();
  const float lg = slg;
  const float v = (lg + logf(u) - log1pf(-u)) * (1.0f / 0.6f);
  float* const dst =
      ws + (l == 0 ? OFF_SL1 : l == 1 ? OFF_SL3 : OFF_SL5);
  dst[idx] = w / (1.0f + expf(-v));
}

// ---------------------------------------------------------------------------
// K2: per-batch chain (round-1 known-good). 64 blocks x 1024 threads.
// X and S = dis*X in LDS ping-pong; hot k-loop reads S; combine applies
// 0.1/0.45*dis_j and refreshes both. Head reads final X from LDS.
// ---------------------------------------------------------------------------
__global__ __launch_bounds__(1024) void batch_chain(
    const float* __restrict__ x0g, const float* __restrict__ ws,
    const float* __restrict__ lin_w, const float* __restrict__ lin_b,
    const float* __restrict__ fc_w, const float* __restrict__ fc_b,
    float* __restrict__ out) {
  const int b = blockIdx.x, tid = threadIdx.x;
  __shared__ float xbuf[2][NN_ * 8];   // X (unscaled), 16 KB
  __shared__ float sbuf[2][NN_ * 8];   // S = dis*X,    16 KB
  __shared__ float part[4 * NN_ * 8];  // 32 KB (reused by head)
  __shared__ float sdis[NN_];          // 1 KB
  float* Xc = xbuf[0];
  float* Xn = xbuf[1];
  float* Sc = sbuf[0];
  float* Sn = sbuf[1];

  for (int ii = tid; ii < NN_; ii += 1024) sdis[ii] = ws[OFF_DIS + ii];
  // stage input x[b] (layout [b*256+i][5]) into padded LDS rows [i][8]
  for (int idx = tid; idx < NN_ * FF_; idx += 1024) {
    const int i = idx / 5, f = idx - 5 * i;
    Xc[i * 8 + f] = x0g[b * (NN_ * FF_) + idx];
  }
  __syncthreads();
  for (int idx = tid; idx < 2048; idx += 1024)
    Sc[idx] = sdis[idx >> 3] * Xc[idx];   // pad lanes garbage, never read
  __syncthreads();

  const int q = tid >> 8;      // k-quarter 0..3
  const int j = tid & 255;     // output node
  const int k0 = q * 64;

#pragma unroll
  for (int l = 0; l < 5; ++l) {
    const float* __restrict__ Op =
        ws + (l == 0 ? OFF_SL1 : l == 2 ? OFF_SL3 : l == 4 ? OFF_SL5 : OFF_SLA)
        + j;
    float4 a03 = {0.f, 0.f, 0.f, 0.f};
    float a4 = 0.f;
#pragma unroll 8
    for (int k = k0; k < k0 + 64; ++k) {
      const float wv = Op[k * NN_];                     // coalesced global
      const float4 xv = *(const float4*)(Sc + k * 8);   // LDS broadcast
      const float x4 = Sc[k * 8 + 4];
      a03.x += wv * xv.x; a03.y += wv * xv.y;
      a03.z += wv * xv.z; a03.w += wv * xv.w;
      a4 += wv * x4;
    }
    *(float4*)(part + tid * 8) = a03;   // part[q][j][0..3]
    part[tid * 8 + 4] = a4;
    __syncthreads();
    // combine quarters: 2048 padded entries (pad f=5..7 garbage, never read)
    for (int idx = tid; idx < 2048; idx += 1024) {
      const float sum = part[idx] + part[2048 + idx] + part[4096 + idx] +
                        part[6144 + idx];
      const float dj = sdis[idx >> 3];
      float y = 0.1f * Xc[idx] + 0.45f * dj * sum;
      if (l == 2) y = fmaxf(y, 0.f);
      Xn[idx] = y;
      Sn[idx] = dj * y;
    }
    __syncthreads();
    float* tp = Xc; Xc = Xn; Xn = tp;
    tp = Sc; Sc = Sn; Sn = tp;
  }

  // head: Xc holds O (256 x 5, padded 8). relu(O@lin_w+lin_b) -> pool -> fc.
  const int k = tid & 127, seg = tid >> 7;  // 8 segs x 32 rows
  const float lw0 = lin_w[0 * 128 + k];
  const float lw1 = lin_w[1 * 128 + k];
  const float lw2 = lin_w[2 * 128 + k];
  const float lw3 = lin_w[3 * 128 + k];
  const float lw4 = lin_w[4 * 128 + k];
  const float lb = lin_b[k];
  float acc = 0.f;
  const int j0 = seg * 32;
#pragma unroll 4
  for (int jj = j0; jj < j0 + 32; ++jj) {
    const float4 ov = *(const float4*)(Xc + jj * 8);  // LDS broadcast
    const float o4 = Xc[jj * 8 + 4];
    const float vv = lb + lw0 * ov.x + lw1 * ov.y + lw2 * ov.z +
                     lw3 * ov.w + lw4 * o4;
    acc += fmaxf(vv, 0.f);
  }
  part[seg * 128 + k] = acc;
  __syncthreads();
  if (tid < 128) {
    float s = 0.f;
#pragma unroll
    for (int s8 = 0; s8 < 8; ++s8) s += part[s8 * 128 + tid];
    part[tid] = s;  // pooled[k]
  }
  __syncthreads();
  if (tid < 3) {
    float s = fc_b[tid];
    for (int kk = 0; kk < 128; ++kk) s += part[kk] * fc_w[kk * 3 + tid];
    out[b * 3 + tid] = s;
  }
}

// ---------------------------------------------------------------------------
extern "C" void kernel_launch(void* const* d_in, const int* in_sizes, int n_in,
                              void* d_out, int out_size, void* d_ws,
                              size_t ws_size, hipStream_t stream) {
  const float* x      = (const float*)d_in[0];
  const float* p      = (const float*)d_in[1];
  const float* a_uc   = (const float*)d_in[2];
  const float* b_uc   = (const float*)d_in[3];
  const float* u_pi   = (const float*)d_in[4];
  const float* u_rb   = (const float*)d_in[5];
  const float* lin_w  = (const float*)d_in[6];
  const float* lin_b  = (const float*)d_in[7];
  const float* fc_w   = (const float*)d_in[8];
  const float* fc_b   = (const float*)d_in[9];
  // d_in[10] edge_index, d_in[11] batch: fully deterministic, never read.
  float* out = (float*)d_out;
  float* ws  = (float*)d_ws;

  build_all<<<1024, 256, 0, stream>>>(p, u_rb, a_uc, b_uc, u_pi, ws, out);
  batch_chain<<<64, 1024, 0, stream>>>(x, ws, lin_w, lin_b, fc_w, fc_b, out);
}

// Round 4
// 126.607 us; speedup vs baseline: 1.2773x; 1.0363x over previous
//
#include <hip/hip_runtime.h>
#include <math.h>

#define NN_ 256      // nodes per graph
#define BB_ 64       // batch
#define FF_ 5        // features
#define NE_ 65536    // NN_*NN_

// workspace layout in floats (~1 MB, L2/L3-resident)
// Operators stored DE-NORMALIZED and transposed: Op[k*256+j] = pure weight
//   SLA = w, SL1 = z0*w, SL3 = z1*w, SL5 = z2*w   (no dis, no 0.45, no diag)
// Chain applies  y_j = 0.1*x_j + 0.45*dis_j * sum_k Op[k,j]*(dis_k*x_k).
#define OFF_SLA 0        // pure w
#define OFF_SL1 65536    // z0*w
#define OFF_SL3 131072   // z1*w
#define OFF_SL5 196608   // z2*w
#define OFF_DIS 262144   // 256 floats

// ---------------------------------------------------------------------------
// K1: fused build (round-1 known-good: 256 blocks x 256 threads).
// Block i = operator row i. One p-row gather serves BOTH the deg reduction
// (dis_i) and the four operator writes. Block 0 lanes 0..2 emit the scalar
// tail (kld_loss, drop_rates).
// ---------------------------------------------------------------------------
__global__ __launch_bounds__(256) void build_all(
    const float* __restrict__ p, const float* __restrict__ u_rb,
    const float* __restrict__ a_uc, const float* __restrict__ b_uc,
    const float* __restrict__ u_pi, float* __restrict__ ws,
    float* __restrict__ out) {
  const int i = blockIdx.x, j = threadIdx.x;
  const int t = (i >= j) ? (i * (i + 1) / 2 + j) : (j * (j + 1) / 2 + i);
  const float w = p[t];

  __shared__ float sh[NN_];
  __shared__ float slg[3];
  __shared__ float skld[3];
  sh[j] = fabsf(w);

  if (j < 3) {
    const int l = j;
    const float au = fmaxf(a_uc[l], -10.0f);
    const float bu = fminf(fmaxf(b_uc[l], -10.0f), 50.0f);
    const float a = log1pf(expf(au));
    const float b = log1pf(expf(bu));
    const float up = fminf(fmaxf(u_pi[l], 1e-6f), 1.0f - 1e-6f);
    const float pi = powf(1.0f - powf(up, 1.0f / b), 1.0f / a);
    slg[l] = logf(pi) - log1pf(-pi);
    if (i == 0) {
      out[193 + l] = pi;  // drop_rates
      float x = b, dg = 0.0f;
      while (x < 6.0f) { dg -= 1.0f / x; x += 1.0f; }
      const float inv = 1.0f / x, inv2 = inv * inv;
      dg += logf(x) - 0.5f * inv
            - inv2 * (1.0f / 12.0f - inv2 * (1.0f / 120.0f - inv2 * (1.0f / 252.0f)));
      const float euler = 0.577215664901532f;
      skld[l] = (1.0f - 0.8f / a) * (-euler - dg - 1.0f / b)
                + logf(a * b + 1e-10f) - logf(0.8f) - (b - 1.0f) / b;
    }
  }
  __syncthreads();

  // deg_i = sum_j |W[i,j]| via LDS tree reduction over the row we just loaded
  for (int s = NN_ / 2; s > 0; s >>= 1) {
    if (j < s) sh[j] += sh[j + s];
    __syncthreads();
  }
  if (j == 0) {
    const float deg = sh[0];
    ws[OFF_DIS + i] = (deg > 0.0f) ? (1.0f / sqrtf(deg)) : 0.0f;
    if (i == 0) out[192] = skld[0] + skld[1] + skld[2];  // kld_loss
  }

  // pure (un-normalized) operators; coalesced u_rb reads and ws writes
  const float lg0 = slg[0];
  const float lg1 = slg[1];
  const float lg2 = slg[2];
  const int idx = i * NN_ + j;
  const float inv_temp = 1.0f / 0.6f;

  ws[OFF_SLA + idx] = w;

  float u, v;
  u = fminf(fmaxf(u_rb[0 * NE_ + idx], 1e-6f), 1.0f - 1e-6f);
  v = (lg0 + logf(u) - log1pf(-u)) * inv_temp;
  ws[OFF_SL1 + idx] = w / (1.0f + expf(-v));

  u = fminf(fmaxf(u_rb[1 * NE_ + idx], 1e-6f), 1.0f - 1e-6f);
  v = (lg1 + logf(u) - log1pf(-u)) * inv_temp;
  ws[OFF_SL3 + idx] = w / (1.0f + expf(-v));

  u = fminf(fmaxf(u_rb[2 * NE_ + idx], 1e-6f), 1.0f - 1e-6f);
  v = (lg2 + logf(u) - log1pf(-u)) * inv_temp;
  ws[OFF_SL5 + idx] = w / (1.0f + expf(-v));
}

// ---------------------------------------------------------------------------
// K2: per-batch chain. 64 blocks x 1024 threads. X and S = dis*X in LDS
// ping-pong. k-loop is LDS-ISSUE bound (broadcast reads), so each thread
// now computes TWO j-columns (j0, j0+128) sharing one broadcast pair per
// k-row -> LDS instructions per output halved. k-axis split 8 ways
// (32 k per thread); 8 partial sets (64 KB) combined per stage.
// Total static LDS 97.25 KB (< 160 KB/CU on gfx950).
// ---------------------------------------------------------------------------
__global__ __launch_bounds__(1024) void batch_chain(
    const float* __restrict__ x0g, const float* __restrict__ ws,
    const float* __restrict__ lin_w, const float* __restrict__ lin_b,
    const float* __restrict__ fc_w, const float* __restrict__ fc_b,
    float* __restrict__ out) {
  const int b = blockIdx.x, tid = threadIdx.x;
  __shared__ float xbuf[2][NN_ * 8];   // X (unscaled), 16 KB
  __shared__ float sbuf[2][NN_ * 8];   // S = dis*X,    16 KB
  __shared__ float part[8 * NN_ * 8];  // 64 KB: [kq][j][f] (reused by head)
  __shared__ float sdis[NN_];          // 1 KB
  float* Xc = xbuf[0];
  float* Xn = xbuf[1];
  float* Sc = sbuf[0];
  float* Sn = sbuf[1];

  for (int ii = tid; ii < NN_; ii += 1024) sdis[ii] = ws[OFF_DIS + ii];
  // stage input x[b] (layout [b*256+i][5]) into padded LDS rows [i][8]
  for (int idx = tid; idx < NN_ * FF_; idx += 1024) {
    const int i = idx / 5, f = idx - 5 * i;
    Xc[i * 8 + f] = x0g[b * (NN_ * FF_) + idx];
  }
  __syncthreads();
  for (int idx = tid; idx < 2048; idx += 1024)
    Sc[idx] = sdis[idx >> 3] * Xc[idx];   // pad lanes garbage, never read
  __syncthreads();

  const int q = tid >> 7;       // k-eighth 0..7
  const int j0 = tid & 127;     // first output node (second = j0+128)
  const int k0 = q * 32;

#pragma unroll
  for (int l = 0; l < 5; ++l) {
    const float* __restrict__ Op =
        ws + (l == 0 ? OFF_SL1 : l == 2 ? OFF_SL3 : l == 4 ? OFF_SL5 : OFF_SLA)
        + j0;
    float4 p03 = {0.f, 0.f, 0.f, 0.f};
    float4 r03 = {0.f, 0.f, 0.f, 0.f};
    float p4 = 0.f, r4 = 0.f;
#pragma unroll 8
    for (int k = k0; k < k0 + 32; ++k) {
      const float w0 = Op[k * NN_];                     // coalesced (L2)
      const float w1 = Op[k * NN_ + 128];               // coalesced (L2)
      const float4 xv = *(const float4*)(Sc + k * 8);   // LDS broadcast
      const float x4 = Sc[k * 8 + 4];                   // LDS broadcast
      p03.x += w0 * xv.x; p03.y += w0 * xv.y;
      p03.z += w0 * xv.z; p03.w += w0 * xv.w; p4 += w0 * x4;
      r03.x += w1 * xv.x; r03.y += w1 * xv.y;
      r03.z += w1 * xv.z; r03.w += w1 * xv.w; r4 += w1 * x4;
    }
    // part[q][j][0..4]; pads f=5..7 garbage, feed only pad lanes
    float* const pp0 = part + (q * NN_ + j0) * 8;
    float* const pp1 = part + (q * NN_ + j0 + 128) * 8;
    *(float4*)pp0 = p03; pp0[4] = p4;
    *(float4*)pp1 = r03; pp1[4] = r4;
    __syncthreads();
    // combine 8 k-eighths: 2048 padded entries
    for (int idx = tid; idx < 2048; idx += 1024) {
      float sum = part[idx];
#pragma unroll
      for (int qq = 1; qq < 8; ++qq) sum += part[qq * 2048 + idx];
      const float dj = sdis[idx >> 3];
      float y = 0.1f * Xc[idx] + 0.45f * dj * sum;
      if (l == 2) y = fmaxf(y, 0.f);
      Xn[idx] = y;
      Sn[idx] = dj * y;
    }
    __syncthreads();
    float* tp = Xc; Xc = Xn; Xn = tp;
    tp = Sc; Sc = Sn; Sn = tp;
  }

  // head: Xc holds O (256 x 5, padded 8). relu(O@lin_w+lin_b) -> pool -> fc.
  const int k = tid & 127, seg = tid >> 7;  // 8 segs x 32 rows
  const float lw0 = lin_w[0 * 128 + k];
  const float lw1 = lin_w[1 * 128 + k];
  const float lw2 = lin_w[2 * 128 + k];
  const float lw3 = lin_w[3 * 128 + k];
  const float lw4 = lin_w[4 * 128 + k];
  const float lb = lin_b[k];
  float acc = 0.f;
  const int r0 = seg * 32;
#pragma unroll 4
  for (int jj = r0; jj < r0 + 32; ++jj) {
    const float4 ov = *(const float4*)(Xc + jj * 8);  // LDS broadcast
    const float o4 = Xc[jj * 8 + 4];
    const float vv = lb + lw0 * ov.x + lw1 * ov.y + lw2 * ov.z +
                     lw3 * ov.w + lw4 * o4;
    acc += fmaxf(vv, 0.f);
  }
  part[seg * 128 + k] = acc;
  __syncthreads();
  if (tid < 128) {
    float s = 0.f;
#pragma unroll
    for (int s8 = 0; s8 < 8; ++s8) s += part[s8 * 128 + tid];
    part[tid] = s;  // pooled[k]
  }
  __syncthreads();
  if (tid < 3) {
    float s = fc_b[tid];
    for (int kk = 0; kk < 128; ++kk) s += part[kk] * fc_w[kk * 3 + tid];
    out[b * 3 + tid] = s;
  }
}

// ---------------------------------------------------------------------------
extern "C" void kernel_launch(void* const* d_in, const int* in_sizes, int n_in,
                              void* d_out, int out_size, void* d_ws,
                              size_t ws_size, hipStream_t stream) {
  const float* x      = (const float*)d_in[0];
  const float* p      = (const float*)d_in[1];
  const float* a_uc   = (const float*)d_in[2];
  const float* b_uc   = (const float*)d_in[3];
  const float* u_pi   = (const float*)d_in[4];
  const float* u_rb   = (const float*)d_in[5];
  const float* lin_w  = (const float*)d_in[6];
  const float* lin_b  = (const float*)d_in[7];
  const float* fc_w   = (const float*)d_in[8];
  const float* fc_b   = (const float*)d_in[9];
  // d_in[10] edge_index, d_in[11] batch: fully deterministic, never read.
  float* out = (float*)d_out;
  float* ws  = (float*)d_ws;

  build_all<<<256, 256, 0, stream>>>(p, u_rb, a_uc, b_uc, u_pi, ws, out);
  batch_chain<<<64, 1024, 0, stream>>>(x, ws, lin_w, lin_b, fc_w, fc_b, out);
}